// Round 2
// baseline (93.003 us; speedup 1.0000x reference)
//
#include <hip/hip_runtime.h>

// QuantLinearMarlin: out[16,8192] = x[16,8192] @ dequant(qweight[1024,8192], scales[64,8192]) + bias
//   dequant: w[k,n] = (nibble(qweight[k/8,n], k%8) - 8) * scales[k/128, n]
// HARNESS DTYPES: reference is fp16 -> canonicalized to float32. x/scales/bias/out are float*.
//
// Design (round 2):
//  - f16 MFMA 16x16x32: B-fragment lane(quad,c) holds k=quad*8+j for col c == one packed
//    int32 of qweight -> global->reg->packed-fp16 dequant->MFMA. No LDS for A/B.
//  - Marlin trick: ((q>>4p)&0x000F000F)|0x64006400 = fp16 pair (1024+nib_p, 1024+nib_{p+4});
//    exact -1032 subtract, then *s in v_pk math. The (p,p+4) k-permutation is mirrored in A
//    by packing cvt_pkrtz(f_p, f_{p+4}) -> contraction unchanged.
//  - 256 blocks x 1024 thr (16 waves = 4/SIMD). Block: 32-wide N tile. Wave: 16x32 out tile,
//    K chunk of 512 (16-way K split). LDS reduce + bias epilogue, fp32 accumulate throughout.

#define K_DIM 8192
#define N_DIM 8192

typedef _Float16 h2 __attribute__((ext_vector_type(2)));
typedef _Float16 h8 __attribute__((ext_vector_type(8)));
typedef float f32x4 __attribute__((ext_vector_type(4)));

union H8U { unsigned u[4]; h8 h; };

__device__ __forceinline__ unsigned pkrtz_u(float a, float b) {
  return __builtin_bit_cast(unsigned, __builtin_amdgcn_cvt_pkrtz(a, b));
}

__global__ __launch_bounds__(1024, 4) void qlin_kernel(
    const float* __restrict__ x,       // [16][8192]
    const int* __restrict__ qw,        // [1024][8192]
    const float* __restrict__ scales,  // [64][8192]
    const float* __restrict__ bias,    // [8192]
    float* __restrict__ out) {         // [16][8192]
  __shared__ float red[16][512];

  const int tid = threadIdx.x;
  const int wave = tid >> 6;   // 0..15 : K-split index
  const int lane = tid & 63;
  const int c = lane & 15;     // fragment column (B col / C col); also A row index m
  const int quad = lane >> 4;  // 0..3
  const int nb = blockIdx.x * 32;

  f32x4 acc0 = {0.f, 0.f, 0.f, 0.f};  // cols nb + 2c
  f32x4 acc1 = {0.f, 0.f, 0.f, 0.f};  // cols nb + 2c + 1

  // A: x[m=c][k = wave*512 + step*32 + quad*8 + j], 8 floats per lane per step
  const float* xp = x + (size_t)c * K_DIM + wave * 512 + quad * 8;
  // B: qw[row = wave*64 + step*4 + quad][nb + 2c .. +1]
  const int* qp = qw + (size_t)(wave * 64 + quad) * N_DIM + nb + 2 * c;
  // scales row = k/128 = wave*4 + g
  const float* sp = scales + (size_t)(wave * 4) * N_DIM + nb + 2 * c;

  const h2 koff = __builtin_bit_cast(h2, 0x64086408u);  // (1032.0h, 1032.0h)

#pragma unroll
  for (int g = 0; g < 4; ++g) {       // 4 groups of 128 k per wave
    float2 sv = *(const float2*)sp;   // scales for even/odd column
    h2 s0 = __builtin_bit_cast(h2, pkrtz_u(sv.x, sv.x));
    h2 s1 = __builtin_bit_cast(h2, pkrtz_u(sv.y, sv.y));
#pragma unroll
    for (int it = 0; it < 4; ++it) {  // 4 k-steps of 32 per group
      int2 q2 = *(const int2*)qp;
      float4 xa = *(const float4*)xp;
      float4 xb = *(const float4*)(xp + 4);
      H8U a, b0, b1;
      // A packed in (p, p+4) k-order to match B's nibble pairing
      a.u[0] = pkrtz_u(xa.x, xb.x);
      a.u[1] = pkrtz_u(xa.y, xb.y);
      a.u[2] = pkrtz_u(xa.z, xb.z);
      a.u[3] = pkrtz_u(xa.w, xb.w);
      unsigned qa = (unsigned)q2.x, qb = (unsigned)q2.y;
#pragma unroll
      for (int p = 0; p < 4; ++p) {
        unsigned t0 = ((qa >> (4 * p)) & 0x000F000Fu) | 0x64006400u;
        unsigned t1 = ((qb >> (4 * p)) & 0x000F000Fu) | 0x64006400u;
        h2 w0 = (__builtin_bit_cast(h2, t0) - koff) * s0;  // (nib-8)*s, sub exact
        h2 w1 = (__builtin_bit_cast(h2, t1) - koff) * s1;
        b0.u[p] = __builtin_bit_cast(unsigned, w0);
        b1.u[p] = __builtin_bit_cast(unsigned, w1);
      }
      acc0 = __builtin_amdgcn_mfma_f32_16x16x32_f16(a.h, b0.h, acc0, 0, 0, 0);
      acc1 = __builtin_amdgcn_mfma_f32_16x16x32_f16(a.h, b1.h, acc1, 0, 0, 0);
      qp += 4 * N_DIM;
      xp += 32;
    }
    sp += N_DIM;
  }

  // C/D layout: col = lane&15 (=c), row m = quad*4 + reg
#pragma unroll
  for (int r = 0; r < 4; ++r) {
    int m = quad * 4 + r;
    red[wave][m * 32 + 2 * c] = acc0[r];
    red[wave][m * 32 + 2 * c + 1] = acc1[r];
  }
  __syncthreads();

  // 512 threads: one (m, j) output each; sum 16 K-split partials + bias
  if (tid < 512) {
    int j = tid & 31;
    float v = 0.f;
#pragma unroll
    for (int w = 0; w < 16; ++w) v += red[w][tid];
    int n = nb + j;
    v += bias[n];
    out[(size_t)(tid >> 5) * N_DIM + n] = v;
  }
}

extern "C" void kernel_launch(void* const* d_in, const int* in_sizes, int n_in,
                              void* d_out, int out_size, void* d_ws, size_t ws_size,
                              hipStream_t stream) {
  const float* x      = (const float*)d_in[0];  // [16,8192] f32 (fp16 canonicalized)
  const int* qw       = (const int*)d_in[1];    // [1024,8192] i32
  const float* scales = (const float*)d_in[2];  // [64,8192] f32
  const float* bias   = (const float*)d_in[3];  // [8192] f32
  float* out          = (float*)d_out;          // [16,8192] f32

  qlin_kernel<<<256, 1024, 0, stream>>>(x, qw, scales, bias, out);
}